// Round 5
// baseline (173.808 us; speedup 1.0000x reference)
//
#include <hip/hip_runtime.h>

// DA-RNN decoder: 256 blocks (1/CU) x 1024 threads, 32 sequential steps.
// Whh f16 in LDS (128KB, swizzled rows). 3 barriers/step:
//  ph1: [G: Whh c=0..7 | U: A=W1a@[h;c] (reg f16 weights)]           B1
//  ph2: [G: Whh c=8..15 + store gdot | U: logits (tanh dot, f16)]    B2
//  ph3: [wave8: softmax -> y_tilde (q-trick) -> LSTM pointwise,
//        cell state + Wih in wave8 registers]                        B3
// ctx materialized once after the loop from the final attn weights.
// [h;c] kept as 4 bank-shifted f16 copies (stride 272) -> conflict-free fans.

#define TT 32

typedef _Float16 h2_t __attribute__((ext_vector_type(2)));
typedef _Float16 h4_t __attribute__((ext_vector_type(4)));
typedef _Float16 h8_t __attribute__((ext_vector_type(8)));

#if __has_builtin(__builtin_amdgcn_fdot2)
#define FDOT2(a, b, c) __builtin_amdgcn_fdot2((a), (b), (c), false)
#else
static __device__ __forceinline__ float FDOT2(h2_t a, h2_t b, float c) {
    return c + (float)a[0] * (float)b[0] + (float)a[1] * (float)b[1];
}
#endif

__device__ __forceinline__ float dot_h8(h8_t w, h8_t v, float acc) {
    acc = FDOT2(__builtin_shufflevector(w, w, 0, 1), __builtin_shufflevector(v, v, 0, 1), acc);
    acc = FDOT2(__builtin_shufflevector(w, w, 2, 3), __builtin_shufflevector(v, v, 2, 3), acc);
    acc = FDOT2(__builtin_shufflevector(w, w, 4, 5), __builtin_shufflevector(v, v, 4, 5), acc);
    acc = FDOT2(__builtin_shufflevector(w, w, 6, 7), __builtin_shufflevector(v, v, 6, 7), acc);
    return acc;
}
__device__ __forceinline__ h8_t pk8(float4 a, float4 b) {
    h8_t r;
    r[0] = (_Float16)a.x; r[1] = (_Float16)a.y; r[2] = (_Float16)a.z; r[3] = (_Float16)a.w;
    r[4] = (_Float16)b.x; r[5] = (_Float16)b.y; r[6] = (_Float16)b.z; r[7] = (_Float16)b.w;
    return r;
}
__device__ __forceinline__ float fast_tanh(float x) {  // |x| bounded ~12 by data scale
    float e = __expf(2.f * x);
    return 1.f - __fdividef(2.f, e + 1.f);
}
__device__ __forceinline__ float fast_sig(float x) {
    return __fdividef(1.f, 1.f + __expf(-x));
}

__global__ __launch_bounds__(1024, 4) void decoder_kernel(
    const float* __restrict__ enc_g,  // [B,32,128]
    const float* __restrict__ yh_g,   // [B,32,1]
    const float* __restrict__ W1,     // [128,384] cols [h|c|enc]
    const float* __restrict__ b1,     // [128]
    const float* __restrict__ W2,     // [1,128]
    const float* __restrict__ b2,     // [1]
    const float* __restrict__ Wih,    // [512,1]
    const float* __restrict__ Whh,    // [512,128]
    const float* __restrict__ bih,    // [512]
    const float* __restrict__ bhh,    // [512]
    const float* __restrict__ fcW,    // [1,129]
    const float* __restrict__ fcB,    // [1]
    const float* __restrict__ fcfW,   // [1,256]
    const float* __restrict__ fcfB,   // [1]
    float* __restrict__ out)          // [B,1]
{
    __shared__ __align__(16) h8_t s_whh8[512 * 16];        // 131072 B, swizzled
    __shared__ __align__(16) _Float16 s_enc16[TT * 136];   // 8704 B
    __shared__ __align__(16) _Float16 s_epre16[TT * 128];  // 8192 B
    __shared__ __align__(16) _Float16 s_hcx[4 * 272];      // [h;c] x4 bank-shifted
    __shared__ __align__(16) _Float16 s_A16[128];
    __shared__ __align__(16) _Float16 s_w216[128];
    __shared__ __align__(16) float s_gdot[512];
    __shared__ __align__(16) _Float16 s_wih16[512];
    __shared__ float s_logit[TT];
    __shared__ float s_q[TT];
    __shared__ float s_att[TT];
    __shared__ float s_yh[TT];
    __shared__ float s_ctx[128];

    const int tid = threadIdx.x;
    const int b = blockIdx.x;
    const int lane = tid & 63;

    // ================= S1: stage enc f16, Whh->LDS f16, W1a->regs ============
    {
        const float4* encp = (const float4*)(enc_g + (size_t)b * TT * 128);
        float4 v = encp[tid];
        int t = tid >> 5, e4 = tid & 31;
        h4_t hv;
        hv[0] = (_Float16)v.x; hv[1] = (_Float16)v.y;
        hv[2] = (_Float16)v.z; hv[3] = (_Float16)v.w;
        *(h4_t*)(s_enc16 + t * 136 + e4 * 4) = hv;
    }
    if (tid < 544) ((unsigned int*)s_hcx)[tid] = 0u;
    if (tid < 128) s_w216[tid] = (_Float16)W2[tid];
    if (tid < TT) s_yh[tid] = yh_g[b * TT + tid];

    float bias_r = 0.f;
    h8_t w1a[8];
    if (tid < 512) {
        const int r = tid, rx = r & 15;
        const float4* wp = (const float4*)(Whh + (size_t)r * 128);
#pragma unroll
        for (int c = 0; c < 16; c++)
            s_whh8[(r << 4) | (c ^ rx)] = pk8(wp[2 * c], wp[2 * c + 1]);
        s_wih16[r] = (_Float16)Wih[r];
        bias_r = bih[r] + bhh[r];
    } else {
        const int u = tid - 512, g = u >> 2, s4 = u & 3;
        const float4* p = (const float4*)(W1 + g * 384 + s4 * 64);
#pragma unroll
        for (int k = 0; k < 8; k++) w1a[k] = pk8(p[2 * k], p[2 * k + 1]);
    }
    const float b2v = b2[0];
    const float fcw128 = fcW[128];
    const float fcbv = fcB[0];
    const float fcfbv = fcfB[0];
    __syncthreads();

    // ========== S2: Epre (all threads), q[t] (tid<256), wave8 wih pack =======
    {
        const int g8 = tid >> 3, s8 = tid & 7;
        const float4* wp = (const float4*)(W1 + g8 * 384 + 256 + s8 * 16);
        h8_t wa = pk8(wp[0], wp[1]);
        h8_t wb = pk8(wp[2], wp[3]);
        const float b1v = b1[g8];
        for (int t = 0; t < TT; t++) {
            const h8_t* ep8 = (const h8_t*)(s_enc16 + t * 136);
            float pa = dot_h8(wa, ep8[s8 * 2], 0.f);
            pa = dot_h8(wb, ep8[s8 * 2 + 1], pa);
            pa += __shfl_xor(pa, 1);
            pa += __shfl_xor(pa, 2);
            pa += __shfl_xor(pa, 4);
            if (s8 == 0) s_epre16[t * 128 + g8] = (_Float16)(pa + b1v);
        }
    }
    if (tid < 256) {  // q[t] = fcW[0:128] . enc[t]
        const int t = tid >> 3, s8 = tid & 7;
        const float4* fp = (const float4*)(fcW + s8 * 16);
        h8_t fa = pk8(fp[0], fp[1]);
        h8_t fb = pk8(fp[2], fp[3]);
        const h8_t* ep8 = (const h8_t*)(s_enc16 + t * 136);
        float pq = dot_h8(fa, ep8[s8 * 2], 0.f);
        pq = dot_h8(fb, ep8[s8 * 2 + 1], pq);
        pq += __shfl_xor(pq, 1);
        pq += __shfl_xor(pq, 2);
        pq += __shfl_xor(pq, 4);
        if (s8 == 0) s_q[t] = pq;
    }
    h8_t w8wih;        // wave8: Wih[j*64+lane], j=0..7
    float c0r = 0.f, c1r = 0.f;  // wave8: cell state c[lane], c[64+lane]
    if (tid >= 512 && tid < 576) {
#pragma unroll
        for (int j = 0; j < 8; j++) w8wih[j] = s_wih16[j * 64 + lane];
    }
    __syncthreads();

    // ============================ scan (32 steps) ============================
    const h8_t* hcp8 = (const h8_t*)s_hcx;  // copy 0 (broadcast reads)

#define GDOT(c, acc) acc = dot_h8(s_whh8[base | ((c) ^ rx)], hcp8[(c)], acc)

    for (int t = 0; t < TT; t++) {
        float pg0 = 0.f, pg1 = 0.f;
        if (tid < 512) {  // G: Whh c=0..7
            const int rx = tid & 15, base = tid << 4;
            GDOT(0, pg0); GDOT(1, pg1); GDOT(2, pg0); GDOT(3, pg1);
            GDOT(4, pg0); GDOT(5, pg1); GDOT(6, pg0); GDOT(7, pg1);
        } else {  // U: A[g] = W1a[g] @ [h;c], copy s4 (bank-disjoint)
            const int u = tid - 512, g = u >> 2, s4 = u & 3;
            const h8_t* hp = (const h8_t*)(s_hcx + s4 * 272);
            float a0 = 0.f, a1 = 0.f;
#pragma unroll
            for (int k = 0; k < 8; k += 2) {
                a0 = dot_h8(w1a[k], hp[s4 * 8 + k], a0);
                a1 = dot_h8(w1a[k + 1], hp[s4 * 8 + k + 1], a1);
            }
            float aa = a0 + a1;
            aa += __shfl_xor(aa, 1);
            aa += __shfl_xor(aa, 2);
            if (s4 == 0) s_A16[g] = (_Float16)aa;
        }
        __syncthreads();  // B1

        if (tid < 512) {  // G: Whh c=8..15, finish gdot
            const int rx = tid & 15, base = tid << 4;
            GDOT(8, pg0); GDOT(9, pg1); GDOT(10, pg0); GDOT(11, pg1);
            GDOT(12, pg0); GDOT(13, pg1); GDOT(14, pg0); GDOT(15, pg1);
            s_gdot[tid] = pg0 + pg1 + bias_r;
        } else {  // logits[tt] = b2 + sum_h w2[h]*tanh(A[h]+Epre[tt][h])
            const int u = tid - 512, tt_ = u >> 4, sub = u & 15;
            h8_t ev = ((const h8_t*)(s_epre16 + tt_ * 128))[sub];
            h8_t av = ((const h8_t*)s_A16)[sub];
            h8_t wv = ((const h8_t*)s_w216)[sub];
            float lp = 0.f;
#pragma unroll
            for (int i = 0; i < 8; i++)
                lp += (float)wv[i] * fast_tanh((float)av[i] + (float)ev[i]);
            lp += __shfl_xor(lp, 1);
            lp += __shfl_xor(lp, 2);
            lp += __shfl_xor(lp, 4);
            lp += __shfl_xor(lp, 8);
            if (sub == 0) s_logit[tt_] = lp + b2v;
        }
        __syncthreads();  // B2

        // ph3 (wave8 only): softmax -> y_tilde -> LSTM pointwise in-wave
        if (tid >= 512 && tid < 576) {
            float el = 0.f, ql = 0.f;
            if (lane < TT) { el = __expf(s_logit[lane]); ql = s_q[lane]; }
            float ss = el, ys = el * ql;
#pragma unroll
            for (int m = 1; m < 64; m <<= 1) {
                ss += __shfl_xor(ss, m);
                ys += __shfl_xor(ys, m);
            }
            float inv = __fdividef(1.f, ss);
            if (lane < TT) s_att[lane] = el * inv;
            float yt = ys * inv + fcw128 * s_yh[t] + fcbv;
            // LSTM: lane handles h[lane], h[64+lane]  (gates i,f,g,o)
            float g0 = s_gdot[lane]       + (float)w8wih[0] * yt;
            float g1 = s_gdot[64 + lane]  + (float)w8wih[1] * yt;
            float g2 = s_gdot[128 + lane] + (float)w8wih[2] * yt;
            float g3 = s_gdot[192 + lane] + (float)w8wih[3] * yt;
            float g4 = s_gdot[256 + lane] + (float)w8wih[4] * yt;
            float g5 = s_gdot[320 + lane] + (float)w8wih[5] * yt;
            float g6 = s_gdot[384 + lane] + (float)w8wih[6] * yt;
            float g7 = s_gdot[448 + lane] + (float)w8wih[7] * yt;
            float cn0 = fast_sig(g2) * c0r + fast_sig(g0) * fast_tanh(g4);
            float cn1 = fast_sig(g3) * c1r + fast_sig(g1) * fast_tanh(g5);
            float hn0 = fast_sig(g6) * fast_tanh(cn0);
            float hn1 = fast_sig(g7) * fast_tanh(cn1);
            c0r = cn0; c1r = cn1;
            _Float16 h0 = (_Float16)hn0, h1 = (_Float16)hn1;
            _Float16 cc0 = (_Float16)cn0, cc1 = (_Float16)cn1;
#pragma unroll
            for (int j = 0; j < 4; j++) {
                _Float16* bp = s_hcx + j * 272;
                bp[lane] = h0;
                bp[64 + lane] = h1;
                bp[128 + lane] = cc0;
                bp[192 + lane] = cc1;
            }
        }
        __syncthreads();  // B3
    }
#undef GDOT

    // ====================== epilogue: ctx, final linear ======================
    if (tid < 128) {
        float acc = 0.f;
#pragma unroll 8
        for (int t = 0; t < TT; t++) acc += s_att[t] * (float)s_enc16[t * 136 + tid];
        s_ctx[tid] = acc;
    }
    __syncthreads();
    if (tid < 64) {
        float p = fcfW[lane] * (float)s_hcx[lane] +
                  fcfW[64 + lane] * (float)s_hcx[64 + lane] +
                  fcfW[128 + lane] * s_ctx[lane] +
                  fcfW[192 + lane] * s_ctx[64 + lane];
#pragma unroll
        for (int m = 1; m < 64; m <<= 1) p += __shfl_xor(p, m);
        if (lane == 0) out[b] = p + fcfbv + s_yh[TT - 1];
    }
}

extern "C" void kernel_launch(void* const* d_in, const int* in_sizes, int n_in,
                              void* d_out, int out_size, void* d_ws, size_t ws_size,
                              hipStream_t stream) {
    decoder_kernel<<<256, 1024, 0, stream>>>(
        (const float*)d_in[0], (const float*)d_in[1], (const float*)d_in[2],
        (const float*)d_in[3], (const float*)d_in[4], (const float*)d_in[5],
        (const float*)d_in[6], (const float*)d_in[7], (const float*)d_in[8],
        (const float*)d_in[9], (const float*)d_in[10], (const float*)d_in[11],
        (const float*)d_in[12], (const float*)d_in[13], (float*)d_out);
}

// Round 6
// 173.647 us; speedup vs baseline: 1.0009x; 1.0009x over previous
//
#include <hip/hip_runtime.h>

// DA-RNN decoder: 256 blocks (1/CU) x 512 threads (8 waves), 32 steps in-block.
// Thread r owns W_hh gate-row r IN REGISTERS (16 x h8 = 64 VGPR, f16) and its
// gdot never leaves registers. W1a quarters in LDS (64KB, XOR-swizzled).
// __launch_bounds__(512,2): 2 waves/EU -> 256-VGPR budget; ask ~120.
// Phases/step: ph1 [gdot(reg) + A=W1a@[h;c]] B1; ph2 [logits] B2;
// ph3 [EVERY wave: redundant softmax -> y_tilde(q-trick) -> act_r=gate(gdot
//      + wih_r*yt), wave-uniform gate fn] B3; ph4 [128 thr: pointwise LSTM,
//      c in registers] B4.  ctx materialized once after the loop.

#define TT 32

typedef _Float16 h2_t __attribute__((ext_vector_type(2)));
typedef _Float16 h4_t __attribute__((ext_vector_type(4)));
typedef _Float16 h8_t __attribute__((ext_vector_type(8)));

#if __has_builtin(__builtin_amdgcn_fdot2)
#define FDOT2(a, b, c) __builtin_amdgcn_fdot2((a), (b), (c), false)
#else
static __device__ __forceinline__ float FDOT2(h2_t a, h2_t b, float c) {
    return c + (float)a[0] * (float)b[0] + (float)a[1] * (float)b[1];
}
#endif

__device__ __forceinline__ float dot_h8(h8_t w, h8_t v, float acc) {
    acc = FDOT2(__builtin_shufflevector(w, w, 0, 1), __builtin_shufflevector(v, v, 0, 1), acc);
    acc = FDOT2(__builtin_shufflevector(w, w, 2, 3), __builtin_shufflevector(v, v, 2, 3), acc);
    acc = FDOT2(__builtin_shufflevector(w, w, 4, 5), __builtin_shufflevector(v, v, 4, 5), acc);
    acc = FDOT2(__builtin_shufflevector(w, w, 6, 7), __builtin_shufflevector(v, v, 6, 7), acc);
    return acc;
}
__device__ __forceinline__ h8_t pk8(float4 a, float4 b) {
    h8_t r;
    r[0] = (_Float16)a.x; r[1] = (_Float16)a.y; r[2] = (_Float16)a.z; r[3] = (_Float16)a.w;
    r[4] = (_Float16)b.x; r[5] = (_Float16)b.y; r[6] = (_Float16)b.z; r[7] = (_Float16)b.w;
    return r;
}
__device__ __forceinline__ float fast_tanh(float x) {
    float e = __expf(2.f * x);
    return 1.f - __fdividef(2.f, e + 1.f);
}
__device__ __forceinline__ float fast_sig(float x) {
    return __fdividef(1.f, 1.f + __expf(-x));
}

__global__ __launch_bounds__(512, 2) void decoder_kernel(
    const float* __restrict__ enc_g,  // [B,32,128]
    const float* __restrict__ yh_g,   // [B,32,1]
    const float* __restrict__ W1,     // [128,384] cols [h|c|enc]
    const float* __restrict__ b1,     // [128]
    const float* __restrict__ W2,     // [1,128]
    const float* __restrict__ b2,     // [1]
    const float* __restrict__ Wih,    // [512,1]
    const float* __restrict__ Whh,    // [512,128]
    const float* __restrict__ bih,    // [512]
    const float* __restrict__ bhh,    // [512]
    const float* __restrict__ fcW,    // [1,129]
    const float* __restrict__ fcB,    // [1]
    const float* __restrict__ fcfW,   // [1,256]
    const float* __restrict__ fcfB,   // [1]
    float* __restrict__ out)          // [B,1]
{
    __shared__ __align__(16) h8_t s_w1a8[512 * 8];         // 65536 B, swizzled
    __shared__ __align__(16) _Float16 s_enc16[TT * 136];   // 8704 B
    __shared__ __align__(16) _Float16 s_epre16[TT * 128];  // 8192 B (dense rows)
    __shared__ __align__(16) _Float16 s_hc[2 * 272];       // 2 copies [h|c|pad]
    __shared__ __align__(16) _Float16 s_A16[128];
    __shared__ __align__(16) _Float16 s_w216[128];
    __shared__ __align__(16) float s_act[512];
    __shared__ float s_logit[TT];
    __shared__ float s_q[TT];
    __shared__ float s_att[TT];
    __shared__ float s_yh[TT];
    __shared__ float s_ctx[128];
    // total ~87 KB -> 1 block/CU

    const int tid = threadIdx.x;
    const int b = blockIdx.x;
    const int lane = tid & 63;
    const int g1 = tid >> 2, s4 = tid & 3;
    const int rx7 = tid & 7;

    // =========================== stage ===========================
    {
        const float4* encp = (const float4*)(enc_g + (size_t)b * TT * 128);
#pragma unroll
        for (int r = 0; r < 2; r++) {
            int gi = tid * 2 + r;  // 0..1023
            float4 v = encp[gi];
            int t = gi >> 5, e4 = gi & 31;
            h4_t hv;
            hv[0] = (_Float16)v.x; hv[1] = (_Float16)v.y;
            hv[2] = (_Float16)v.z; hv[3] = (_Float16)v.w;
            *(h4_t*)(s_enc16 + t * 136 + e4 * 4) = hv;
        }
    }
    if (tid < 272) ((unsigned int*)s_hc)[tid] = 0u;
    if (tid < 128) s_w216[tid] = (_Float16)W2[tid];
    if (tid < TT) s_yh[tid] = yh_g[b * TT + tid];

    // Whh row tid -> registers (f16)
    h8_t whhreg[16];
    {
        const float4* wp = (const float4*)(Whh + (size_t)tid * 128);
#pragma unroll
        for (int k = 0; k < 16; k++) whhreg[k] = pk8(wp[2 * k], wp[2 * k + 1]);
    }
    const float wih_r = Wih[tid];
    const float bias_r = bih[tid] + bhh[tid];

    // W1a quarter (row g1, cols s4*64..+64) -> LDS, XOR-swizzled chunks
    {
        const float4* p = (const float4*)(W1 + g1 * 384 + s4 * 64);
#pragma unroll
        for (int k = 0; k < 8; k++)
            s_w1a8[tid * 8 + (k ^ rx7)] = pk8(p[2 * k], p[2 * k + 1]);
    }
    const float b2v = b2[0];
    const float fcw128 = fcW[128];
    const float fcbv = fcB[0];
    const float fcfbv = fcfB[0];
    __syncthreads();

    // ============ Epre[t][g1] = b1[g1] + W1b[g1]@enc[t]  (4 thr/row) =========
    {
        const float4* wp = (const float4*)(W1 + g1 * 384 + 256 + s4 * 32);
        h8_t wa = pk8(wp[0], wp[1]), wb = pk8(wp[2], wp[3]);
        h8_t wc = pk8(wp[4], wp[5]), wd = pk8(wp[6], wp[7]);
        const float b1v = b1[g1];
        for (int t = 0; t < TT; t++) {
            const h8_t* ep8 = (const h8_t*)(s_enc16 + t * 136);
            float pa = dot_h8(wa, ep8[s4 * 4 + 0], 0.f);
            float pb = dot_h8(wb, ep8[s4 * 4 + 1], 0.f);
            pa = dot_h8(wc, ep8[s4 * 4 + 2], pa);
            pb = dot_h8(wd, ep8[s4 * 4 + 3], pb);
            float pp = pa + pb;
            pp += __shfl_xor(pp, 1);
            pp += __shfl_xor(pp, 2);
            if (s4 == 0) s_epre16[t * 128 + g1] = (_Float16)(pp + b1v);
        }
    }
    if (tid < 128) {  // q[t] = fcW[0:128] . enc[t]
        const int tq = tid >> 2, sq = tid & 3;
        const float4* fp = (const float4*)(fcW + sq * 32);
        h8_t fa = pk8(fp[0], fp[1]), fb = pk8(fp[2], fp[3]);
        h8_t fc2 = pk8(fp[4], fp[5]), fd = pk8(fp[6], fp[7]);
        const h8_t* ep8 = (const h8_t*)(s_enc16 + tq * 136);
        float pa = dot_h8(fa, ep8[sq * 4 + 0], 0.f);
        float pb = dot_h8(fb, ep8[sq * 4 + 1], 0.f);
        pa = dot_h8(fc2, ep8[sq * 4 + 2], pa);
        pb = dot_h8(fd, ep8[sq * 4 + 3], pb);
        float pq = pa + pb;
        pq += __shfl_xor(pq, 1);
        pq += __shfl_xor(pq, 2);
        if (sq == 0) s_q[tq] = pq;
    }
    float c_reg = 0.f;  // tid<128: fp32 cell state
    __syncthreads();

    // ============================ scan (32 steps) ============================
    for (int t = 0; t < TT; t++) {
        // ph1a: gdot = bias + Whh[r]@h (register weights, broadcast h reads)
        float gdot;
        {
            const h8_t* hp = (const h8_t*)s_hc;  // copy0: h = chunks 0..15
            float a0 = 0.f, a1 = 0.f, a2 = 0.f, a3 = 0.f;
#pragma unroll
            for (int k = 0; k < 2; k++) {
                a0 = dot_h8(whhreg[4 * k + 0], hp[4 * k + 0], a0);
                a1 = dot_h8(whhreg[4 * k + 1], hp[4 * k + 1], a1);
                a2 = dot_h8(whhreg[4 * k + 2], hp[4 * k + 2], a2);
                a3 = dot_h8(whhreg[4 * k + 3], hp[4 * k + 3], a3);
            }
            __builtin_amdgcn_sched_barrier(0);  // cap transient h-load registers
#pragma unroll
            for (int k = 2; k < 4; k++) {
                a0 = dot_h8(whhreg[4 * k + 0], hp[4 * k + 0], a0);
                a1 = dot_h8(whhreg[4 * k + 1], hp[4 * k + 1], a1);
                a2 = dot_h8(whhreg[4 * k + 2], hp[4 * k + 2], a2);
                a3 = dot_h8(whhreg[4 * k + 3], hp[4 * k + 3], a3);
            }
            gdot = (a0 + a1) + (a2 + a3) + bias_r;
        }
        __builtin_amdgcn_sched_barrier(0);
        // ph1b: A[g1] += W1a[g1][s4*64..] @ [h;c]  (LDS weights, 4-thr reduce)
        {
            const h8_t* hcp = (const h8_t*)(s_hc + (s4 >> 1) * 272);
            const h8_t* wp8 = s_w1a8 + tid * 8;
            float a0 = 0.f, a1 = 0.f;
#pragma unroll
            for (int k = 0; k < 4; k++) {
                a0 = dot_h8(wp8[(2 * k) ^ rx7], hcp[s4 * 8 + 2 * k], a0);
                a1 = dot_h8(wp8[(2 * k + 1) ^ rx7], hcp[s4 * 8 + 2 * k + 1], a1);
            }
            float aa = a0 + a1;
            aa += __shfl_xor(aa, 1);
            aa += __shfl_xor(aa, 2);
            if (s4 == 0) s_A16[g1] = (_Float16)aa;
        }
        __syncthreads();  // B1

        // ph2: logits[tt] = b2 + sum_h w2[h]*tanh(A[h]+Epre[tt][h])
        {
            const int tt_ = tid >> 4, sub = tid & 15;
            h8_t ev = ((const h8_t*)(s_epre16 + tt_ * 128))[sub];
            h8_t av = ((const h8_t*)s_A16)[sub];
            h8_t wv = ((const h8_t*)s_w216)[sub];
            float lp = 0.f;
#pragma unroll
            for (int i = 0; i < 8; i++)
                lp += (float)wv[i] * fast_tanh((float)av[i] + (float)ev[i]);
            lp += __shfl_xor(lp, 1);
            lp += __shfl_xor(lp, 2);
            lp += __shfl_xor(lp, 4);
            lp += __shfl_xor(lp, 8);
            if (sub == 0) s_logit[tt_] = lp + b2v;
        }
        __syncthreads();  // B2

        // ph3: EVERY wave: redundant softmax -> y_tilde -> own gate activation
        float act;
        {
            float el = __expf(s_logit[lane & 31]);
            float ql = s_q[lane & 31];
            float ss = el, ys = el * ql;
#pragma unroll
            for (int m = 1; m <= 16; m <<= 1) {
                ss += __shfl_xor(ss, m);
                ys += __shfl_xor(ys, m);
            }
            float inv = __fdividef(1.f, ss);
            if (t == TT - 1 && tid < TT) s_att[tid] = el * inv;
            float yt = ys * inv + fcw128 * s_yh[t] + fcbv;
            float gv = gdot + wih_r * yt;
            act = ((tid >> 7) == 2) ? fast_tanh(gv) : fast_sig(gv);  // g-gate: tanh
            s_act[tid] = act;
        }
        __syncthreads();  // B3

        // ph4: pointwise LSTM by threads 0..127 (own act == act_i)
        if (tid < 128) {
            float af = s_act[128 + tid];
            float ag = s_act[256 + tid];
            float ao = s_act[384 + tid];
            float cn = af * c_reg + act * ag;
            float hn = ao * fast_tanh(cn);
            c_reg = cn;
            _Float16 hh = (_Float16)hn, cc = (_Float16)cn;
            s_hc[tid] = hh;
            s_hc[128 + tid] = cc;
            s_hc[272 + tid] = hh;
            s_hc[400 + tid] = cc;
        }
        __syncthreads();  // B4
    }

    // ============================== epilogue =================================
    if (tid < 128) {
        float acc = 0.f;
#pragma unroll 8
        for (int t2 = 0; t2 < TT; t2++) acc += s_att[t2] * (float)s_enc16[t2 * 136 + tid];
        s_ctx[tid] = acc;
    }
    __syncthreads();
    if (tid < 64) {
        float p = fcfW[lane] * (float)s_hc[lane] +
                  fcfW[64 + lane] * (float)s_hc[64 + lane] +
                  fcfW[128 + lane] * s_ctx[lane] +
                  fcfW[192 + lane] * s_ctx[64 + lane];
#pragma unroll
        for (int m = 1; m < 64; m <<= 1) p += __shfl_xor(p, m);
        if (lane == 0) out[b] = p + fcfbv + s_yh[TT - 1];
    }
}

extern "C" void kernel_launch(void* const* d_in, const int* in_sizes, int n_in,
                              void* d_out, int out_size, void* d_ws, size_t ws_size,
                              hipStream_t stream) {
    decoder_kernel<<<256, 512, 0, stream>>>(
        (const float*)d_in[0], (const float*)d_in[1], (const float*)d_in[2],
        (const float*)d_in[3], (const float*)d_in[4], (const float*)d_in[5],
        (const float*)d_in[6], (const float*)d_in[7], (const float*)d_in[8],
        (const float*)d_in[9], (const float*)d_in[10], (const float*)d_in[11],
        (const float*)d_in[12], (const float*)d_in[13], (float*)d_out);
}

// Round 7
// 165.955 us; speedup vs baseline: 1.0473x; 1.0463x over previous
//
#include <hip/hip_runtime.h>

// DA-RNN decoder: 256 blocks (1/CU) x 512 threads, 32 sequential steps in-block.
// BOTH weight matrices register-resident as f16 (Whh row: 64 VGPR; W1a quarter:
// 32 VGPR) under __launch_bounds__(512,2) -> 256-VGPR budget (honored, R6-proven).
// 3 barriers/step (dataflow minimum):
//  ph1: gdot = bias + Whh[r]@h (reg, broadcast h) interleaved with
//       A[g1] = W1a-quarter @ [h;c] (reg, 2-way-free LDS reads); f/g/o gdot->LDS. B1
//  ph2: logits[t] = b2 + W2 . tanh(A + Epre[t])  (16 thr per t).              B2
//  ph3: thr 0..127: softmax -> y_tilde (q-trick) -> all 4 gate acts
//       (i-gate gdot in-register) -> LSTM pointwise -> h,c (f16, 2 copies).   B3
// ctx materialized once after the loop. No sched_barriers (compiler ILP).

#define TT 32

typedef _Float16 h2_t __attribute__((ext_vector_type(2)));
typedef _Float16 h4_t __attribute__((ext_vector_type(4)));
typedef _Float16 h8_t __attribute__((ext_vector_type(8)));

#if __has_builtin(__builtin_amdgcn_fdot2)
#define FDOT2(a, b, c) __builtin_amdgcn_fdot2((a), (b), (c), false)
#else
static __device__ __forceinline__ float FDOT2(h2_t a, h2_t b, float c) {
    return c + (float)a[0] * (float)b[0] + (float)a[1] * (float)b[1];
}
#endif

__device__ __forceinline__ float dot_h8(h8_t w, h8_t v, float acc) {
    acc = FDOT2(__builtin_shufflevector(w, w, 0, 1), __builtin_shufflevector(v, v, 0, 1), acc);
    acc = FDOT2(__builtin_shufflevector(w, w, 2, 3), __builtin_shufflevector(v, v, 2, 3), acc);
    acc = FDOT2(__builtin_shufflevector(w, w, 4, 5), __builtin_shufflevector(v, v, 4, 5), acc);
    acc = FDOT2(__builtin_shufflevector(w, w, 6, 7), __builtin_shufflevector(v, v, 6, 7), acc);
    return acc;
}
__device__ __forceinline__ h8_t pk8(float4 a, float4 b) {
    h8_t r;
    r[0] = (_Float16)a.x; r[1] = (_Float16)a.y; r[2] = (_Float16)a.z; r[3] = (_Float16)a.w;
    r[4] = (_Float16)b.x; r[5] = (_Float16)b.y; r[6] = (_Float16)b.z; r[7] = (_Float16)b.w;
    return r;
}
__device__ __forceinline__ float fast_tanh(float x) {
    float e = __expf(2.f * x);
    return 1.f - __fdividef(2.f, e + 1.f);
}
__device__ __forceinline__ float fast_sig(float x) {
    return __fdividef(1.f, 1.f + __expf(-x));
}

__global__ __launch_bounds__(512, 2) void decoder_kernel(
    const float* __restrict__ enc_g,  // [B,32,128]
    const float* __restrict__ yh_g,   // [B,32,1]
    const float* __restrict__ W1,     // [128,384] cols [h|c|enc]
    const float* __restrict__ b1,     // [128]
    const float* __restrict__ W2,     // [1,128]
    const float* __restrict__ b2,     // [1]
    const float* __restrict__ Wih,    // [512,1]
    const float* __restrict__ Whh,    // [512,128]
    const float* __restrict__ bih,    // [512]
    const float* __restrict__ bhh,    // [512]
    const float* __restrict__ fcW,    // [1,129]
    const float* __restrict__ fcB,    // [1]
    const float* __restrict__ fcfW,   // [1,256]
    const float* __restrict__ fcfB,   // [1]
    float* __restrict__ out)          // [B,1]
{
    __shared__ __align__(16) _Float16 s_enc16[TT * 136];   // 8704 B
    __shared__ __align__(16) _Float16 s_epre16[TT * 128];  // 8192 B
    __shared__ __align__(16) _Float16 s_hc[2 * 272];       // 2 copies [h|c|pad]
    __shared__ __align__(16) _Float16 s_A16[128];
    __shared__ __align__(16) _Float16 s_w216[128];
    __shared__ __align__(16) float s_gdot3[384];           // f,g,o gate dots
    __shared__ float s_logit[TT];
    __shared__ float s_q[TT];
    __shared__ float s_att[TT];
    __shared__ float s_yh[TT];
    __shared__ float s_ctx[128];
    // ~22 KB

    const int tid = threadIdx.x;
    const int b = blockIdx.x;
    const int lane = tid & 63;
    const int g1 = tid >> 2, s4 = tid & 3;

    // =========================== stage ===========================
    {
        const float4* encp = (const float4*)(enc_g + (size_t)b * TT * 128);
#pragma unroll
        for (int r = 0; r < 2; r++) {
            int gi = tid * 2 + r;  // 0..1023
            float4 v = encp[gi];
            int t = gi >> 5, e4 = gi & 31;
            h4_t hv;
            hv[0] = (_Float16)v.x; hv[1] = (_Float16)v.y;
            hv[2] = (_Float16)v.z; hv[3] = (_Float16)v.w;
            *(h4_t*)(s_enc16 + t * 136 + e4 * 4) = hv;
        }
    }
    if (tid < 272) ((unsigned int*)s_hc)[tid] = 0u;
    if (tid < 128) s_w216[tid] = (_Float16)W2[tid];
    if (tid < TT) s_yh[tid] = yh_g[b * TT + tid];

    // Whh row tid -> registers (f16)
    h8_t whhreg[16];
    {
        const float4* wp = (const float4*)(Whh + (size_t)tid * 128);
#pragma unroll
        for (int k = 0; k < 16; k++) whhreg[k] = pk8(wp[2 * k], wp[2 * k + 1]);
    }
    const float bias_r = bih[tid] + bhh[tid];

    // W1a quarter (row g1, cols s4*64..+64) -> registers (f16)
    h8_t w1areg[8];
    {
        const float4* p = (const float4*)(W1 + g1 * 384 + s4 * 64);
#pragma unroll
        for (int k = 0; k < 8; k++) w1areg[k] = pk8(p[2 * k], p[2 * k + 1]);
    }

    // thr 0..127: per-gate Wih scalars (i,f,g,o)
    float wih0 = 0.f, wih1 = 0.f, wih2 = 0.f, wih3 = 0.f;
    if (tid < 128) {
        wih0 = Wih[tid];
        wih1 = Wih[128 + tid];
        wih2 = Wih[256 + tid];
        wih3 = Wih[384 + tid];
    }
    const float b2v = b2[0];
    const float fcw128 = fcW[128];
    const float fcbv = fcB[0];
    const float fcfbv = fcfB[0];
    __syncthreads();

    // ============ Epre[t][g1] = b1[g1] + W1b[g1]@enc[t]  (4 thr/row) =========
    {
        const float4* wp = (const float4*)(W1 + g1 * 384 + 256 + s4 * 32);
        h8_t wa = pk8(wp[0], wp[1]), wb = pk8(wp[2], wp[3]);
        h8_t wc = pk8(wp[4], wp[5]), wd = pk8(wp[6], wp[7]);
        const float b1v = b1[g1];
        for (int t = 0; t < TT; t++) {
            const h8_t* ep8 = (const h8_t*)(s_enc16 + t * 136);
            float pa = dot_h8(wa, ep8[s4 * 4 + 0], 0.f);
            float pb = dot_h8(wb, ep8[s4 * 4 + 1], 0.f);
            pa = dot_h8(wc, ep8[s4 * 4 + 2], pa);
            pb = dot_h8(wd, ep8[s4 * 4 + 3], pb);
            float pp = pa + pb;
            pp += __shfl_xor(pp, 1);
            pp += __shfl_xor(pp, 2);
            if (s4 == 0) s_epre16[t * 128 + g1] = (_Float16)(pp + b1v);
        }
    }
    if (tid < 128) {  // q[t] = fcW[0:128] . enc[t]
        const int tq = tid >> 2, sq = tid & 3;
        const float4* fp = (const float4*)(fcW + sq * 32);
        h8_t fa = pk8(fp[0], fp[1]), fb = pk8(fp[2], fp[3]);
        h8_t fc2 = pk8(fp[4], fp[5]), fd = pk8(fp[6], fp[7]);
        const h8_t* ep8 = (const h8_t*)(s_enc16 + tq * 136);
        float pa = dot_h8(fa, ep8[sq * 4 + 0], 0.f);
        float pb = dot_h8(fb, ep8[sq * 4 + 1], 0.f);
        pa = dot_h8(fc2, ep8[sq * 4 + 2], pa);
        pb = dot_h8(fd, ep8[sq * 4 + 3], pb);
        float pq = pa + pb;
        pq += __shfl_xor(pq, 1);
        pq += __shfl_xor(pq, 2);
        if (sq == 0) s_q[tq] = pq;
    }
    float c_reg = 0.f;  // tid<128: fp32 cell state
    __syncthreads();

    // ============================ scan (32 steps) ============================
    for (int t = 0; t < TT; t++) {
        // ---- ph1: gdot (reg weights, broadcast h) + A (reg weights) ----
        float gdot, aa;
        {
            const h8_t* hp0 = (const h8_t*)s_hc;                      // uniform
            const h8_t* hpA = (const h8_t*)(s_hc + (s4 & 1) * 272);   // 2-way max
            float a0 = 0.f, a1 = 0.f;
            float g0 = 0.f, g1v = 0.f, g2 = 0.f, g3 = 0.f;
#pragma unroll
            for (int k = 0; k < 4; k++) {
                a0 = dot_h8(w1areg[2 * k], hpA[s4 * 8 + 2 * k], a0);
                a1 = dot_h8(w1areg[2 * k + 1], hpA[s4 * 8 + 2 * k + 1], a1);
                g0 = dot_h8(whhreg[4 * k + 0], hp0[4 * k + 0], g0);
                g1v = dot_h8(whhreg[4 * k + 1], hp0[4 * k + 1], g1v);
                g2 = dot_h8(whhreg[4 * k + 2], hp0[4 * k + 2], g2);
                g3 = dot_h8(whhreg[4 * k + 3], hp0[4 * k + 3], g3);
            }
            gdot = (g0 + g1v) + (g2 + g3) + bias_r;
            aa = a0 + a1;
            aa += __shfl_xor(aa, 1);
            aa += __shfl_xor(aa, 2);
        }
        if (s4 == 0) s_A16[g1] = (_Float16)aa;
        if (tid >= 128) s_gdot3[tid - 128] = gdot;
        __syncthreads();  // B1

        // ---- ph2: logits[tt] = b2 + sum_h w2[h]*tanh(A[h]+Epre[tt][h]) ----
        {
            const int tt_ = tid >> 4, sub = tid & 15;
            h8_t ev = ((const h8_t*)(s_epre16 + tt_ * 128))[sub];
            h8_t av = ((const h8_t*)s_A16)[sub];
            h8_t wv = ((const h8_t*)s_w216)[sub];
            float lp = 0.f;
#pragma unroll
            for (int i = 0; i < 8; i++)
                lp += (float)wv[i] * fast_tanh((float)av[i] + (float)ev[i]);
            lp += __shfl_xor(lp, 1);
            lp += __shfl_xor(lp, 2);
            lp += __shfl_xor(lp, 4);
            lp += __shfl_xor(lp, 8);
            if (sub == 0) s_logit[tt_] = lp + b2v;
        }
        __syncthreads();  // B2

        // ---- ph3 (thr 0..127): softmax -> y_tilde -> 4 gates -> LSTM ----
        if (tid < 128) {
            float el = __expf(s_logit[lane & 31]);
            float ql = s_q[lane & 31];
            float ss = el, ys = el * ql;
#pragma unroll
            for (int m = 1; m <= 16; m <<= 1) {
                ss += __shfl_xor(ss, m);
                ys += __shfl_xor(ys, m);
            }
            float inv = __fdividef(1.f, ss);
            if (t == TT - 1 && tid < TT) s_att[tid] = el * inv;
            float yt = ys * inv + fcw128 * s_yh[t] + fcbv;
            float gi_ = gdot + wih0 * yt;  // i-gate dot still in-register
            float gf_ = s_gdot3[tid] + wih1 * yt;
            float gg_ = s_gdot3[128 + tid] + wih2 * yt;
            float go_ = s_gdot3[256 + tid] + wih3 * yt;
            float cn = fast_sig(gf_) * c_reg + fast_sig(gi_) * fast_tanh(gg_);
            float hn = fast_sig(go_) * fast_tanh(cn);
            c_reg = cn;
            _Float16 hh = (_Float16)hn, cc = (_Float16)cn;
            s_hc[tid] = hh;
            s_hc[128 + tid] = cc;
            s_hc[272 + tid] = hh;
            s_hc[400 + tid] = cc;
        }
        __syncthreads();  // B3
    }

    // ============================== epilogue =================================
    if (tid < 128) {
        float acc = 0.f;
#pragma unroll 8
        for (int t2 = 0; t2 < TT; t2++) acc += s_att[t2] * (float)s_enc16[t2 * 136 + tid];
        s_ctx[tid] = acc;
    }
    __syncthreads();
    if (tid < 64) {
        float p = fcfW[lane] * (float)s_hc[lane] +
                  fcfW[64 + lane] * (float)s_hc[64 + lane] +
                  fcfW[128 + lane] * s_ctx[lane] +
                  fcfW[192 + lane] * s_ctx[64 + lane];
#pragma unroll
        for (int m = 1; m < 64; m <<= 1) p += __shfl_xor(p, m);
        if (lane == 0) out[b] = p + fcfbv + s_yh[TT - 1];
    }
}

extern "C" void kernel_launch(void* const* d_in, const int* in_sizes, int n_in,
                              void* d_out, int out_size, void* d_ws, size_t ws_size,
                              hipStream_t stream) {
    decoder_kernel<<<256, 512, 0, stream>>>(
        (const float*)d_in[0], (const float*)d_in[1], (const float*)d_in[2],
        (const float*)d_in[3], (const float*)d_in[4], (const float*)d_in[5],
        (const float*)d_in[6], (const float*)d_in[7], (const float*)d_in[8],
        (const float*)d_in[9], (const float*)d_in[10], (const float*)d_in[11],
        (const float*)d_in[12], (const float*)d_in[13], (float*)d_out);
}